// Round 7
// baseline (596.712 us; speedup 1.0000x reference)
//
#include <hip/hip_runtime.h>

// Problem constants (T=64, B=32, I=128, H=256, alpha=0.2)
#define TT 64
#define BB 32
#define II 128
#define HH 256
#define MM (TT*BB)   // 2048

typedef __bf16  bf16x8  __attribute__((ext_vector_type(8)));
typedef float   f32x16  __attribute__((ext_vector_type(16)));
typedef _Float16 half2v __attribute__((ext_vector_type(2)));

__device__ __forceinline__ float bf2f(unsigned short u) {
    union { unsigned int i; float f; } v; v.i = ((unsigned int)u) << 16; return v.f;
}
__device__ __forceinline__ unsigned short f2bf(float f) {
    union { float f; unsigned int i; } v; v.f = f;
    unsigned int r = v.i + 0x7fffu + ((v.i >> 16) & 1u);
    return (unsigned short)(r >> 16);
}

// Dual-dtype loaders: external tensors may be fp32 or bf16; runtime flag decides.
struct F8 { float v[8]; };
__device__ __forceinline__ F8 load8(const void* base, int idx, int isf32) {
    F8 r;
    if (isf32) {
        const float4* p = (const float4*)((const float*)base + idx);
        float4 a = p[0], b = p[1];
        r.v[0]=a.x; r.v[1]=a.y; r.v[2]=a.z; r.v[3]=a.w;
        r.v[4]=b.x; r.v[5]=b.y; r.v[6]=b.z; r.v[7]=b.w;
    } else {
        uint4 u = *(const uint4*)((const unsigned short*)base + idx);
        const unsigned short* p = (const unsigned short*)&u;
#pragma unroll
        for (int j = 0; j < 8; ++j) r.v[j] = bf2f(p[j]);
    }
    return r;
}
__device__ __forceinline__ float load1(const void* base, int idx, int isf32) {
    return isf32 ? ((const float*)base)[idx]
                 : bf2f(((const unsigned short*)base)[idx]);
}

__device__ __forceinline__ float fdot2f(half2v a, half2v b, float c) {
#if __has_builtin(__builtin_amdgcn_fdot2)
    return __builtin_amdgcn_fdot2(a, b, c, false);
#else
    return c + (float)a.x*(float)b.x + (float)a.y*(float)b.y;
#endif
}

// ---------------------------------------------------------------------------
// K0: dtype sniffer (fp32 read as ushorts -> ~25% have exponent >= 0xC0).
// ---------------------------------------------------------------------------
__global__ __launch_bounds__(256) void k0_sniff(
    const unsigned short* __restrict__ x, int* __restrict__ flag)
{
    __shared__ int cnt;
    if (threadIdx.x == 0) cnt = 0;
    __syncthreads();
    int c = 0;
    for (int i = threadIdx.x; i < 8192; i += 256) {
        unsigned int e = (x[i] >> 7) & 0xFFu;
        if (e >= 0xC0u) ++c;
    }
    atomicAdd(&cnt, c);
    __syncthreads();
    if (threadIdx.x == 0) flag[0] = (cnt > 16) ? 1 : 0;
}

// ---------------------------------------------------------------------------
// K1 v3 (unchanged): weights in VGPRs; two-phase (load blob -> dot) per m-row.
// ---------------------------------------------------------------------------
__global__ __launch_bounds__(256) void k1_proj(
    const void* __restrict__ x,
    const void* __restrict__ w_i2h,
    const void* __restrict__ b_i2h,
    const void* __restrict__ w_i2c,
    const void* __restrict__ b_i2c,
    const int* __restrict__ flagp,
    unsigned short* __restrict__ ip,
    float* __restrict__ cin)
{
    const int isf32 = *flagp;
    const int tid = threadIdx.x;
    const int h = tid;
    const int mbase = blockIdx.x * 32;
    __shared__ __align__(16) _Float16 xs[32][II];   // 8 KB

    half2v w1[II/2], w2[II/2];
#pragma unroll
    for (int c8 = 0; c8 < II/8; ++c8) {
        F8 f1 = load8(w_i2h, h*II + c8*8, isf32);
        F8 f2 = load8(w_i2c, h*II + c8*8, isf32);
#pragma unroll
        for (int j = 0; j < 4; ++j) {
            half2v a; a.x = (_Float16)f1.v[2*j]; a.y = (_Float16)f1.v[2*j+1];
            half2v b; b.x = (_Float16)f2.v[2*j]; b.y = (_Float16)f2.v[2*j+1];
            w1[c8*4 + j] = a;
            w2[c8*4 + j] = b;
        }
    }
    const float bb1 = load1(b_i2h, h, isf32);
    const float bb2 = load1(b_i2c, h, isf32);

    for (int u = tid; u < 32*II; u += 256)
        xs[u >> 7][u & (II-1)] = (_Float16)load1(x, (mbase + (u >> 7))*II + (u & (II-1)), isf32);
    __syncthreads();

    for (int mm = 0; mm < 32; ++mm) {
        const float4* xv4 = (const float4*)xs[mm];   // 16 x float4 = 128 halves
        float4 blob[16];
#pragma unroll
        for (int r = 0; r < 16; ++r) blob[r] = xv4[r];
        float a0=0,a1=0,a2=0,a3=0, c0=0,c1=0,c2=0,c3=0;
#pragma unroll
        for (int r = 0; r < 16; ++r) {
            const half2v* xc = (const half2v*)&blob[r];
            a0 = fdot2f(w1[r*4+0], xc[0], a0);
            a1 = fdot2f(w1[r*4+1], xc[1], a1);
            a2 = fdot2f(w1[r*4+2], xc[2], a2);
            a3 = fdot2f(w1[r*4+3], xc[3], a3);
            c0 = fdot2f(w2[r*4+0], xc[0], c0);
            c1 = fdot2f(w2[r*4+1], xc[1], c1);
            c2 = fdot2f(w2[r*4+2], xc[2], c2);
            c3 = fdot2f(w2[r*4+3], xc[3], c3);
        }
        ip[(mbase+mm)*HH + h]  = f2bf(((a0+a1)+(a2+a3)) + bb1);
        cin[(mbase+mm)*HH + h] = ((c0+c1)+(c2+c3)) + bb2;
    }
}

// ---------------------------------------------------------------------------
// K2 v3 (unchanged): 512 threads, k split in half, two-phase load->dot.
// ---------------------------------------------------------------------------
__global__ __launch_bounds__(512) void k2_ctx(
    const void* __restrict__ w_c2c,
    const void* __restrict__ b_c2c,
    const float* __restrict__ cin,
    const int* __restrict__ ns_ptr,
    const int* __restrict__ flagp,
    unsigned short* __restrict__ ctx_hist,
    void* __restrict__ out_base)
{
    const int isf32 = *flagp;
    const int b = blockIdx.x;
    const int tid = threadIdx.x;
    const int h  = tid & 255;
    const int kh = tid >> 8;
    const int ns = max(1, *ns_ptr);

    __shared__ __align__(16) _Float16 cs[2][HH];
    __shared__ __align__(16) float part[2][HH];

    half2v w[64];
#pragma unroll
    for (int c8 = 0; c8 < 16; ++c8) {
        F8 f = load8(w_c2c, h*HH + kh*128 + c8*8, isf32);
#pragma unroll
        for (int j = 0; j < 4; ++j) {
            half2v hv;
            hv.x = (_Float16)f.v[2*j];
            hv.y = (_Float16)f.v[2*j+1];
            w[c8*4 + j] = hv;
        }
    }
    const float bcc = (kh == 0) ? load1(b_c2c, h, isf32) : 0.0f;
    float ctxv = 0.0f;
    if (kh == 0) cs[0][h] = (_Float16)0.0f;
    __syncthreads();
    int cur = 0;

    for (int t = 0; t < TT; ++t) {
        const float cinv = (kh == 0) ? cin[(t*BB + b)*HH + h] : 0.0f;
        for (int s = 0; s < ns; ++s) {
            if (kh == 0 && s == ns-1) ctx_hist[(t*BB + b)*HH + h] = f2bf(ctxv);
            float4 blob[16];
            const float4* cp4 = (const float4*)cs[cur] + kh*16;
#pragma unroll
            for (int r = 0; r < 16; ++r) blob[r] = cp4[r];
            float p0=0,p1=0,p2=0,p3=0;
#pragma unroll
            for (int r = 0; r < 16; ++r) {
                const half2v* c2 = (const half2v*)&blob[r];
                p0 = fdot2f(w[r*4+0], c2[0], p0);
                p1 = fdot2f(w[r*4+1], c2[1], p1);
                p2 = fdot2f(w[r*4+2], c2[2], p2);
                p3 = fdot2f(w[r*4+3], c2[3], p3);
            }
            part[kh][h] = ((p0+p1)+(p2+p3));
            __syncthreads();
            if (kh == 0) {
                float cnew = fmaxf(part[0][h] + part[1][h] + bcc + cinv, 0.0f);
                ctxv = 0.8f*ctxv + 0.2f*cnew;
                cs[cur^1][h] = (_Float16)ctxv;
            }
            cur ^= 1;
            __syncthreads();
        }
    }
    if (kh == 0) {
        const int cofs = MM*HH + BB*HH + b*HH + h;
        if (isf32) ((float*)out_base)[cofs] = ctxv;
        else       ((unsigned short*)out_base)[cofs] = f2bf(ctxv);
    }
}

// ---------------------------------------------------------------------------
// K3 v6: R6's conflict-free fragment-major layout, with register pressure
// fixed (R6 spilled: 156 MB scratch writes):
//  - areg prefetch confined to the kc loop (no liveness across the epilogue);
//    kc=0 loads fresh at mc top (~600 cyc exposed, x8 = ~2 us).
//  - epilogue rep loop unroll 2 (was full unroll -> hoisted ~30 regs).
// ---------------------------------------------------------------------------
__global__ __launch_bounds__(512, 1) void k3_main(
    const unsigned short* __restrict__ ctx_hist,  // [2048,256] bf16 (internal)
    const void* __restrict__ wc,                  // [65536,256] external
    const void* __restrict__ bc,                  // [65536]     external
    const unsigned short* __restrict__ ip,        // [2048,256] bf16 (internal)
    const int* __restrict__ flagp,
    float* __restrict__ outT)                     // [256 i][2048 m] f32 (ws)
{
    extern __shared__ __align__(16) unsigned char lds[];
    unsigned short* Bs = (unsigned short*)lds;              // 131072 B
    unsigned short* As = (unsigned short*)(lds + 131072);   // 32768 B
    unsigned short* TMh = As;                               // epilogue overlay

    const int isf32 = *flagp;
    const int tid  = threadIdx.x;
    const int lane = tid & 63;
    const int wave = tid >> 6;        // 0..7
    const int i    = blockIdx.x;      // 0..255
    const int mh   = wave & 3;        // m-subblock (64 rows)
    const int jh   = wave >> 2;       // j-half (128 cols)
    const int l31  = lane & 31;
    const int lhi  = lane >> 5;

    // epilogue per-lane bc for cols 4*lane..4*lane+3
    float bcl[4];
#pragma unroll
    for (int q = 0; q < 4; ++q)
        bcl[q] = load1(bc, i*HH + 4*lane + q, isf32);

    // ---- stage B once: fragment-major, conflict-free ----
#pragma unroll
    for (int p = 0; p < 16; ++p) {
        int u = tid + p*512;
        int row = u >> 5, cu = u & 31;
        F8 f = load8(wc, (i*HH + row)*HH + cu*8, isf32);
        unsigned short tmp[8];
#pragma unroll
        for (int j = 0; j < 8; ++j) tmp[j] = f2bf(f.v[j]);
        int unit = cu*256 + (row & ~7) + ((row & 7) ^ (cu & 7));
        *(uint4*)(Bs + unit*8) = *(const uint4*)tmp;
    }
    // first kc's barrier covers B visibility

    for (int mc = 0; mc < 8; ++mc) {
        const int m0 = mc * 256;

        f32x16 acc[2][4];
#pragma unroll
        for (int a = 0; a < 2; ++a)
#pragma unroll
            for (int n = 0; n < 4; ++n)
#pragma unroll
                for (int r = 0; r < 16; ++r) acc[a][n][r] = 0.0f;

        // load A chunk for kc=0 of this mc (latency partially exposed; cheap)
        uint4 areg[4];
#pragma unroll
        for (int p = 0; p < 4; ++p) {
            int u = tid + p*512;
            int row = u >> 3, cu = u & 7;
            areg[p] = *(const uint4*)(ctx_hist + (m0 + row)*HH + cu*8);
        }

#pragma unroll
        for (int kc = 0; kc < 4; ++kc) {
            __syncthreads();   // As readers (MFMA / epilogue TM) done
#pragma unroll
            for (int p = 0; p < 4; ++p) {
                int u = tid + p*512;
                int row = u >> 3, cu = u & 7;
                int unit = cu*256 + (row & ~7) + ((row & 7) ^ cu);
                *(uint4*)(As + unit*8) = areg[p];
            }
            __syncthreads();
            // prefetch next kc of SAME mc (liveness ends with the kc loop)
            if (kc < 3) {
                const unsigned short* src = ctx_hist + m0*HH + (kc+1)*64;
#pragma unroll
                for (int p = 0; p < 4; ++p) {
                    int u = tid + p*512;
                    int row = u >> 3, cu = u & 7;
                    areg[p] = *(const uint4*)(src + row*HH + cu*8);
                }
            }
#pragma unroll
            for (int ks = 0; ks < 4; ++ks) {
                const int cA = ks*2 + lhi;          // 0..7
                const int ra0 = mh*64 + l31;
                const int ra1 = ra0 + 32;
                bf16x8 a0 = *(const bf16x8*)(As + (cA*256 + (ra0 & ~7) + ((ra0 & 7) ^ cA))*8);
                bf16x8 a1 = *(const bf16x8*)(As + (cA*256 + (ra1 & ~7) + ((ra1 & 7) ^ cA))*8);
                const int cB = kc*8 + ks*2 + lhi;   // 0..31
                const int cx = cB & 7;
                const int rb0 = jh*128 +       l31;
                const int rb1 = jh*128 + 32  + l31;
                const int rb2 = jh*128 + 64  + l31;
                const int rb3 = jh*128 + 96  + l31;
                bf16x8 b0 = *(const bf16x8*)(Bs + (cB*256 + (rb0 & ~7) + ((rb0 & 7) ^ cx))*8);
                bf16x8 b1 = *(const bf16x8*)(Bs + (cB*256 + (rb1 & ~7) + ((rb1 & 7) ^ cx))*8);
                bf16x8 b2 = *(const bf16x8*)(Bs + (cB*256 + (rb2 & ~7) + ((rb2 & 7) ^ cx))*8);
                bf16x8 b3 = *(const bf16x8*)(Bs + (cB*256 + (rb3 & ~7) + ((rb3 & 7) ^ cx))*8);
                acc[0][0] = __builtin_amdgcn_mfma_f32_32x32x16_bf16(a0, b0, acc[0][0], 0, 0, 0);
                acc[0][1] = __builtin_amdgcn_mfma_f32_32x32x16_bf16(a0, b1, acc[0][1], 0, 0, 0);
                acc[0][2] = __builtin_amdgcn_mfma_f32_32x32x16_bf16(a0, b2, acc[0][2], 0, 0, 0);
                acc[0][3] = __builtin_amdgcn_mfma_f32_32x32x16_bf16(a0, b3, acc[0][3], 0, 0, 0);
                acc[1][0] = __builtin_amdgcn_mfma_f32_32x32x16_bf16(a1, b0, acc[1][0], 0, 0, 0);
                acc[1][1] = __builtin_amdgcn_mfma_f32_32x32x16_bf16(a1, b1, acc[1][1], 0, 0, 0);
                acc[1][2] = __builtin_amdgcn_mfma_f32_32x32x16_bf16(a1, b2, acc[1][2], 0, 0, 0);
                acc[1][3] = __builtin_amdgcn_mfma_f32_32x32x16_bf16(a1, b3, acc[1][3], 0, 0, 0);
            }
        }

        // ---- epilogue: 4 phases of 64 m-rows; TM bf16 [64][256] on As ----
        __syncthreads();   // last MFMA As reads done
#pragma unroll
        for (int ph = 0; ph < 4; ++ph) {
            if (mh == ph) {
#pragma unroll
                for (int a = 0; a < 2; ++a)
#pragma unroll
                    for (int n = 0; n < 4; ++n) {
                        const int col = jh*128 + n*32 + l31;
#pragma unroll
                        for (int r = 0; r < 16; ++r) {
                            const int rowl = a*32 + (r & 3) + 8*(r >> 2) + 4*lhi;
                            TMh[rowl*256 + col] = f2bf(acc[a][n][r]);
                        }
                    }
            }
            __syncthreads();
#pragma unroll 2
            for (int rep = 0; rep < 8; ++rep) {
                const int rowg = wave*8 + rep;                 // 0..63
                const int g = m0 + ph*64 + rowg;               // global m
                uint2 tm2 = *(const uint2*)(TMh + rowg*256 + 4*lane);
                uint2 ip2 = *(const uint2*)(ip + g*HH + 4*lane);
                const unsigned short* tp = (const unsigned short*)&tm2;
                const unsigned short* pp = (const unsigned short*)&ip2;
                float s = 0.0f;
#pragma unroll
                for (int q = 0; q < 4; ++q)
                    s = fmaf(bf2f(tp[q]) + bcl[q], bf2f(pp[q]), s);
                s += __shfl_xor(s, 1);
                s += __shfl_xor(s, 2);
                s += __shfl_xor(s, 4);
                s += __shfl_xor(s, 8);
                s += __shfl_xor(s, 16);
                s += __shfl_xor(s, 32);
                if (lane == rep) outT[(size_t)i*MM + g] = s;
            }
            __syncthreads();
        }
    }
}

// ---------------------------------------------------------------------------
// K4: transpose outT[256 i][2048 m] f32 -> out[m][i] (+ final-hidden chunk).
// ---------------------------------------------------------------------------
__global__ __launch_bounds__(256) void k4_tr(
    const float* __restrict__ outT,
    const int* __restrict__ flagp,
    void* __restrict__ out)
{
    const int isf32 = *flagp;
    __shared__ float tile[64][65];
    const int m0 = blockIdx.x * 64, i0 = blockIdx.y * 64;
    const int tm = threadIdx.x & 63, tq = threadIdx.x >> 6;   // tq 0..3
#pragma unroll
    for (int rep = 0; rep < 16; ++rep) {
        int il = tq + rep*4;
        tile[il][tm] = outT[(size_t)(i0 + il)*MM + m0 + tm];
    }
    __syncthreads();
#pragma unroll
    for (int rep = 0; rep < 16; ++rep) {
        int ml = tq + rep*4;
        int ii = tm;
        float v = tile[ii][ml];
        int mg = m0 + ml, ig = i0 + ii;
        if (isf32) {
            float* o = (float*)out;
            o[(size_t)mg*HH + ig] = v;
            if (mg >= MM - BB) o[(size_t)MM*HH + (mg - (MM-BB))*HH + ig] = v;
        } else {
            unsigned short* o = (unsigned short*)out;
            unsigned short b = f2bf(v);
            o[(size_t)mg*HH + ig] = b;
            if (mg >= MM - BB) o[(size_t)MM*HH + (mg - (MM-BB))*HH + ig] = b;
        }
    }
}

// ---------------------------------------------------------------------------
extern "C" void kernel_launch(void* const* d_in, const int* in_sizes, int n_in,
                              void* d_out, int out_size, void* d_ws, size_t ws_size,
                              hipStream_t stream) {
    const void* x     = d_in[0];
    const void* w_i2h = d_in[1];
    const void* b_i2h = d_in[2];
    // d_in[3]=w_h2h, d_in[4]=b_h2h: dead code (reference overwrites hidden=transformed)
    const void* w_i2c = d_in[5];
    const void* b_i2c = d_in[6];
    const void* w_c2c = d_in[7];
    const void* b_c2c = d_in[8];
    const void* w_c2t = d_in[9];
    const void* b_c2t = d_in[10];
    const int* ns     = (const int*)d_in[11];

    // ws layout: ip bf16 [2048,256] | ctx_hist bf16 | cin f32 | flag | outT f32
    unsigned short* ip  = (unsigned short*)d_ws;
    unsigned short* ch  = (unsigned short*)((char*)d_ws + (size_t)MM*HH*2);
    float* cin          = (float*)((char*)d_ws + (size_t)MM*HH*4);
    int* flag           = (int*)((char*)d_ws + (size_t)MM*HH*8);
    float* outT         = (float*)((char*)d_ws + (size_t)MM*HH*8 + 1024);

    // allow 160 KiB dynamic LDS for k3 (host-side attribute; capture-safe)
    (void)hipFuncSetAttribute((const void*)k3_main,
                              hipFuncAttributeMaxDynamicSharedMemorySize, 163840);

    k0_sniff<<<1, 256, 0, stream>>>((const unsigned short*)x, flag);
    k1_proj<<<64, 256, 0, stream>>>(x, w_i2h, b_i2h, w_i2c, b_i2c, flag, ip, cin);
    k2_ctx<<<BB, 512, 0, stream>>>(w_c2c, b_c2c, cin, ns, flag, ch, d_out);
    k3_main<<<256, 512, 163840, stream>>>(ch, w_c2t, b_c2t, ip, flag, outT);
    k4_tr<<<dim3(32, 4), 256, 0, stream>>>(outT, flag, d_out);
}

// Round 8
// 467.153 us; speedup vs baseline: 1.2773x; 1.2773x over previous
//
#include <hip/hip_runtime.h>

// Problem constants (T=64, B=32, I=128, H=256, alpha=0.2)
#define TT 64
#define BB 32
#define II 128
#define HH 256
#define MM (TT*BB)   // 2048

typedef __bf16  bf16x8  __attribute__((ext_vector_type(8)));
typedef float   f32x16  __attribute__((ext_vector_type(16)));
typedef _Float16 half2v __attribute__((ext_vector_type(2)));

__device__ __forceinline__ float bf2f(unsigned short u) {
    union { unsigned int i; float f; } v; v.i = ((unsigned int)u) << 16; return v.f;
}
__device__ __forceinline__ unsigned short f2bf(float f) {
    union { float f; unsigned int i; } v; v.f = f;
    unsigned int r = v.i + 0x7fffu + ((v.i >> 16) & 1u);
    return (unsigned short)(r >> 16);
}

// Dual-dtype loaders: external tensors may be fp32 or bf16; runtime flag decides.
struct F8 { float v[8]; };
__device__ __forceinline__ F8 load8(const void* base, int idx, int isf32) {
    F8 r;
    if (isf32) {
        const float4* p = (const float4*)((const float*)base + idx);
        float4 a = p[0], b = p[1];
        r.v[0]=a.x; r.v[1]=a.y; r.v[2]=a.z; r.v[3]=a.w;
        r.v[4]=b.x; r.v[5]=b.y; r.v[6]=b.z; r.v[7]=b.w;
    } else {
        uint4 u = *(const uint4*)((const unsigned short*)base + idx);
        const unsigned short* p = (const unsigned short*)&u;
#pragma unroll
        for (int j = 0; j < 8; ++j) r.v[j] = bf2f(p[j]);
    }
    return r;
}
__device__ __forceinline__ float load1(const void* base, int idx, int isf32) {
    return isf32 ? ((const float*)base)[idx]
                 : bf2f(((const unsigned short*)base)[idx]);
}

__device__ __forceinline__ float fdot2f(half2v a, half2v b, float c) {
#if __has_builtin(__builtin_amdgcn_fdot2)
    return __builtin_amdgcn_fdot2(a, b, c, false);
#else
    return c + (float)a.x*(float)b.x + (float)a.y*(float)b.y;
#endif
}

// ---------------------------------------------------------------------------
// K0: dtype sniffer (fp32 read as ushorts -> ~25% have exponent >= 0xC0).
// ---------------------------------------------------------------------------
__global__ __launch_bounds__(256) void k0_sniff(
    const unsigned short* __restrict__ x, int* __restrict__ flag)
{
    __shared__ int cnt;
    if (threadIdx.x == 0) cnt = 0;
    __syncthreads();
    int c = 0;
    for (int i = threadIdx.x; i < 8192; i += 256) {
        unsigned int e = (x[i] >> 7) & 0xFFu;
        if (e >= 0xC0u) ++c;
    }
    atomicAdd(&cnt, c);
    __syncthreads();
    if (threadIdx.x == 0) flag[0] = (cnt > 16) ? 1 : 0;
}

// ---------------------------------------------------------------------------
// K1 v3 (unchanged): weights in VGPRs; two-phase (load blob -> dot) per m-row.
// ---------------------------------------------------------------------------
__global__ __launch_bounds__(256) void k1_proj(
    const void* __restrict__ x,
    const void* __restrict__ w_i2h,
    const void* __restrict__ b_i2h,
    const void* __restrict__ w_i2c,
    const void* __restrict__ b_i2c,
    const int* __restrict__ flagp,
    unsigned short* __restrict__ ip,
    float* __restrict__ cin)
{
    const int isf32 = *flagp;
    const int tid = threadIdx.x;
    const int h = tid;
    const int mbase = blockIdx.x * 32;
    __shared__ __align__(16) _Float16 xs[32][II];   // 8 KB

    half2v w1[II/2], w2[II/2];
#pragma unroll
    for (int c8 = 0; c8 < II/8; ++c8) {
        F8 f1 = load8(w_i2h, h*II + c8*8, isf32);
        F8 f2 = load8(w_i2c, h*II + c8*8, isf32);
#pragma unroll
        for (int j = 0; j < 4; ++j) {
            half2v a; a.x = (_Float16)f1.v[2*j]; a.y = (_Float16)f1.v[2*j+1];
            half2v b; b.x = (_Float16)f2.v[2*j]; b.y = (_Float16)f2.v[2*j+1];
            w1[c8*4 + j] = a;
            w2[c8*4 + j] = b;
        }
    }
    const float bb1 = load1(b_i2h, h, isf32);
    const float bb2 = load1(b_i2c, h, isf32);

    for (int u = tid; u < 32*II; u += 256)
        xs[u >> 7][u & (II-1)] = (_Float16)load1(x, (mbase + (u >> 7))*II + (u & (II-1)), isf32);
    __syncthreads();

    for (int mm = 0; mm < 32; ++mm) {
        const float4* xv4 = (const float4*)xs[mm];   // 16 x float4 = 128 halves
        float4 blob[16];
#pragma unroll
        for (int r = 0; r < 16; ++r) blob[r] = xv4[r];
        float a0=0,a1=0,a2=0,a3=0, c0=0,c1=0,c2=0,c3=0;
#pragma unroll
        for (int r = 0; r < 16; ++r) {
            const half2v* xc = (const half2v*)&blob[r];
            a0 = fdot2f(w1[r*4+0], xc[0], a0);
            a1 = fdot2f(w1[r*4+1], xc[1], a1);
            a2 = fdot2f(w1[r*4+2], xc[2], a2);
            a3 = fdot2f(w1[r*4+3], xc[3], a3);
            c0 = fdot2f(w2[r*4+0], xc[0], c0);
            c1 = fdot2f(w2[r*4+1], xc[1], c1);
            c2 = fdot2f(w2[r*4+2], xc[2], c2);
            c3 = fdot2f(w2[r*4+3], xc[3], c3);
        }
        ip[(mbase+mm)*HH + h]  = f2bf(((a0+a1)+(a2+a3)) + bb1);
        cin[(mbase+mm)*HH + h] = ((c0+c1)+(c2+c3)) + bb2;
    }
}

// ---------------------------------------------------------------------------
// K2 v3 (unchanged): 512 threads, k split in half, two-phase load->dot.
// ---------------------------------------------------------------------------
__global__ __launch_bounds__(512) void k2_ctx(
    const void* __restrict__ w_c2c,
    const void* __restrict__ b_c2c,
    const float* __restrict__ cin,
    const int* __restrict__ ns_ptr,
    const int* __restrict__ flagp,
    unsigned short* __restrict__ ctx_hist,
    void* __restrict__ out_base)
{
    const int isf32 = *flagp;
    const int b = blockIdx.x;
    const int tid = threadIdx.x;
    const int h  = tid & 255;
    const int kh = tid >> 8;
    const int ns = max(1, *ns_ptr);

    __shared__ __align__(16) _Float16 cs[2][HH];
    __shared__ __align__(16) float part[2][HH];

    half2v w[64];
#pragma unroll
    for (int c8 = 0; c8 < 16; ++c8) {
        F8 f = load8(w_c2c, h*HH + kh*128 + c8*8, isf32);
#pragma unroll
        for (int j = 0; j < 4; ++j) {
            half2v hv;
            hv.x = (_Float16)f.v[2*j];
            hv.y = (_Float16)f.v[2*j+1];
            w[c8*4 + j] = hv;
        }
    }
    const float bcc = (kh == 0) ? load1(b_c2c, h, isf32) : 0.0f;
    float ctxv = 0.0f;
    if (kh == 0) cs[0][h] = (_Float16)0.0f;
    __syncthreads();
    int cur = 0;

    for (int t = 0; t < TT; ++t) {
        const float cinv = (kh == 0) ? cin[(t*BB + b)*HH + h] : 0.0f;
        for (int s = 0; s < ns; ++s) {
            if (kh == 0 && s == ns-1) ctx_hist[(t*BB + b)*HH + h] = f2bf(ctxv);
            float4 blob[16];
            const float4* cp4 = (const float4*)cs[cur] + kh*16;
#pragma unroll
            for (int r = 0; r < 16; ++r) blob[r] = cp4[r];
            float p0=0,p1=0,p2=0,p3=0;
#pragma unroll
            for (int r = 0; r < 16; ++r) {
                const half2v* c2 = (const half2v*)&blob[r];
                p0 = fdot2f(w[r*4+0], c2[0], p0);
                p1 = fdot2f(w[r*4+1], c2[1], p1);
                p2 = fdot2f(w[r*4+2], c2[2], p2);
                p3 = fdot2f(w[r*4+3], c2[3], p3);
            }
            part[kh][h] = ((p0+p1)+(p2+p3));
            __syncthreads();
            if (kh == 0) {
                float cnew = fmaxf(part[0][h] + part[1][h] + bcc + cinv, 0.0f);
                ctxv = 0.8f*ctxv + 0.2f*cnew;
                cs[cur^1][h] = (_Float16)ctxv;
            }
            cur ^= 1;
            __syncthreads();
        }
    }
    if (kh == 0) {
        const int cofs = MM*HH + BB*HH + b*HH + h;
        if (isf32) ((float*)out_base)[cofs] = ctxv;
        else       ((unsigned short*)out_base)[cofs] = f2bf(ctxv);
    }
}

// ---------------------------------------------------------------------------
// K3 v7: fix R6/R7's structural spill. A 512-thread block forces 2 waves/SIMD
// -> hard 256-reg/wave cap; the old 64m x 128j wave tile needed 128 acc regs,
// capping arch VGPRs at 128 -> scratch spill (156-168 MB writes). New tile:
// mc = 128 m-rows (16 iterations), wave tile 32m x 128j -> acc = 64 regs,
// arch budget 192. K-chunk = 128 (As 128x128 = 32 KB, 2 kc/mc). Fragment-
// major XOR LDS layouts kept (measured 0 conflicts). Cross-chunk A prefetch
// in VGPRs (16 regs, affordable now).
// ---------------------------------------------------------------------------
__global__ __launch_bounds__(512, 1) void k3_main(
    const unsigned short* __restrict__ ctx_hist,  // [2048,256] bf16 (internal)
    const void* __restrict__ wc,                  // [65536,256] external
    const void* __restrict__ bc,                  // [65536]     external
    const unsigned short* __restrict__ ip,        // [2048,256] bf16 (internal)
    const int* __restrict__ flagp,
    float* __restrict__ outT)                     // [256 i][2048 m] f32 (ws)
{
    extern __shared__ __align__(16) unsigned char lds[];
    unsigned short* Bs = (unsigned short*)lds;              // 131072 B
    unsigned short* As = (unsigned short*)(lds + 131072);   // 32768 B
    unsigned short* TMh = As;                               // epilogue overlay [64][256]

    const int isf32 = *flagp;
    const int tid  = threadIdx.x;
    const int lane = tid & 63;
    const int wave = tid >> 6;        // 0..7
    const int i    = blockIdx.x;      // 0..255
    const int mh   = wave & 3;        // m-subblock (32 rows)
    const int jh   = wave >> 2;       // j-half (128 cols)
    const int l31  = lane & 31;
    const int lhi  = lane >> 5;

    // epilogue per-lane bc for cols 4*lane..4*lane+3
    float bcl[4];
#pragma unroll
    for (int q = 0; q < 4; ++q)
        bcl[q] = load1(bc, i*HH + 4*lane + q, isf32);

    // ---- stage B once: fragment-major, conflict-free ----
#pragma unroll
    for (int p = 0; p < 16; ++p) {
        int u = tid + p*512;
        int row = u >> 5, cu = u & 31;
        F8 f = load8(wc, (i*HH + row)*HH + cu*8, isf32);
        unsigned short tmp[8];
#pragma unroll
        for (int j = 0; j < 8; ++j) tmp[j] = f2bf(f.v[j]);
        int unit = cu*256 + (row & ~7) + ((row & 7) ^ (cu & 7));
        *(uint4*)(Bs + unit*8) = *(const uint4*)tmp;
    }
    // first kc's barrier covers B visibility

    // prefetch chunk 0 (mc=0, kc=0): 128 rows x 128 k
    uint4 areg[4];
#pragma unroll
    for (int p = 0; p < 4; ++p) {
        int u = tid + p*512;
        int row = u >> 4, cu = u & 15;
        areg[p] = *(const uint4*)(ctx_hist + row*HH + cu*8);
    }

    for (int mc = 0; mc < 16; ++mc) {
        const int m0 = mc * 128;

        f32x16 acc[4];
#pragma unroll
        for (int n = 0; n < 4; ++n)
#pragma unroll
            for (int r = 0; r < 16; ++r) acc[n][r] = 0.0f;

#pragma unroll
        for (int kc = 0; kc < 2; ++kc) {
            __syncthreads();   // As readers (MFMA / epilogue TM) done
#pragma unroll
            for (int p = 0; p < 4; ++p) {
                int u = tid + p*512;
                int row = u >> 4, cu = u & 15;
                int unit = cu*128 + (row & ~7) + ((row & 7) ^ (cu & 7));
                *(uint4*)(As + unit*8) = areg[p];
            }
            __syncthreads();
            // prefetch next chunk (linear over 32 chunks of [128 rows x 128 k])
            {
                int nc = mc*2 + kc + 1;
                if (nc < 32) {
                    const unsigned short* src = ctx_hist + (nc >> 1)*128*HH + (nc & 1)*128;
#pragma unroll
                    for (int p = 0; p < 4; ++p) {
                        int u = tid + p*512;
                        int row = u >> 4, cu = u & 15;
                        areg[p] = *(const uint4*)(src + row*HH + cu*8);
                    }
                }
            }
#pragma unroll
            for (int ks = 0; ks < 8; ++ks) {
                const int cA = ks*2 + lhi;          // 0..15
                const int ra = mh*32 + l31;         // 0..127
                bf16x8 a0 = *(const bf16x8*)(As + (cA*128 + (ra & ~7) + ((ra & 7) ^ (cA & 7)))*8);
                const int cB = kc*16 + ks*2 + lhi;  // 0..31
                const int cx = cB & 7;
                const int rb0 = jh*128 +       l31;
                const int rb1 = jh*128 + 32  + l31;
                const int rb2 = jh*128 + 64  + l31;
                const int rb3 = jh*128 + 96  + l31;
                bf16x8 b0 = *(const bf16x8*)(Bs + (cB*256 + (rb0 & ~7) + ((rb0 & 7) ^ cx))*8);
                bf16x8 b1 = *(const bf16x8*)(Bs + (cB*256 + (rb1 & ~7) + ((rb1 & 7) ^ cx))*8);
                bf16x8 b2 = *(const bf16x8*)(Bs + (cB*256 + (rb2 & ~7) + ((rb2 & 7) ^ cx))*8);
                bf16x8 b3 = *(const bf16x8*)(Bs + (cB*256 + (rb3 & ~7) + ((rb3 & 7) ^ cx))*8);
                acc[0] = __builtin_amdgcn_mfma_f32_32x32x16_bf16(a0, b0, acc[0], 0, 0, 0);
                acc[1] = __builtin_amdgcn_mfma_f32_32x32x16_bf16(a0, b1, acc[1], 0, 0, 0);
                acc[2] = __builtin_amdgcn_mfma_f32_32x32x16_bf16(a0, b2, acc[2], 0, 0, 0);
                acc[3] = __builtin_amdgcn_mfma_f32_32x32x16_bf16(a0, b3, acc[3], 0, 0, 0);
            }
        }

        // ---- epilogue: 2 phases of 64 m-rows; TM bf16 [64][256] on As ----
        __syncthreads();   // last MFMA As reads done
#pragma unroll
        for (int ph = 0; ph < 2; ++ph) {
            if ((mh >> 1) == ph) {
#pragma unroll
                for (int n = 0; n < 4; ++n) {
                    const int col = jh*128 + n*32 + l31;
#pragma unroll
                    for (int r = 0; r < 16; ++r) {
                        const int rowl = (mh & 1)*32 + (r & 3) + 8*(r >> 2) + 4*lhi;
                        TMh[rowl*256 + col] = f2bf(acc[n][r]);
                    }
                }
            }
            __syncthreads();
#pragma unroll 2
            for (int rep = 0; rep < 8; ++rep) {
                const int rowg = wave*8 + rep;                 // 0..63
                const int g = m0 + ph*64 + rowg;               // global m
                uint2 tm2 = *(const uint2*)(TMh + rowg*256 + 4*lane);
                uint2 ip2 = *(const uint2*)(ip + g*HH + 4*lane);
                const unsigned short* tp = (const unsigned short*)&tm2;
                const unsigned short* pp = (const unsigned short*)&ip2;
                float s = 0.0f;
#pragma unroll
                for (int q = 0; q < 4; ++q)
                    s = fmaf(bf2f(tp[q]) + bcl[q], bf2f(pp[q]), s);
                s += __shfl_xor(s, 1);
                s += __shfl_xor(s, 2);
                s += __shfl_xor(s, 4);
                s += __shfl_xor(s, 8);
                s += __shfl_xor(s, 16);
                s += __shfl_xor(s, 32);
                if (lane == rep) outT[(size_t)i*MM + g] = s;
            }
            __syncthreads();
        }
    }
}

// ---------------------------------------------------------------------------
// K4: transpose outT[256 i][2048 m] f32 -> out[m][i] (+ final-hidden chunk).
// ---------------------------------------------------------------------------
__global__ __launch_bounds__(256) void k4_tr(
    const float* __restrict__ outT,
    const int* __restrict__ flagp,
    void* __restrict__ out)
{
    const int isf32 = *flagp;
    __shared__ float tile[64][65];
    const int m0 = blockIdx.x * 64, i0 = blockIdx.y * 64;
    const int tm = threadIdx.x & 63, tq = threadIdx.x >> 6;   // tq 0..3
#pragma unroll
    for (int rep = 0; rep < 16; ++rep) {
        int il = tq + rep*4;
        tile[il][tm] = outT[(size_t)(i0 + il)*MM + m0 + tm];
    }
    __syncthreads();
#pragma unroll
    for (int rep = 0; rep < 16; ++rep) {
        int ml = tq + rep*4;
        int ii = tm;
        float v = tile[ii][ml];
        int mg = m0 + ml, ig = i0 + ii;
        if (isf32) {
            float* o = (float*)out;
            o[(size_t)mg*HH + ig] = v;
            if (mg >= MM - BB) o[(size_t)MM*HH + (mg - (MM-BB))*HH + ig] = v;
        } else {
            unsigned short* o = (unsigned short*)out;
            unsigned short b = f2bf(v);
            o[(size_t)mg*HH + ig] = b;
            if (mg >= MM - BB) o[(size_t)MM*HH + (mg - (MM-BB))*HH + ig] = b;
        }
    }
}

// ---------------------------------------------------------------------------
extern "C" void kernel_launch(void* const* d_in, const int* in_sizes, int n_in,
                              void* d_out, int out_size, void* d_ws, size_t ws_size,
                              hipStream_t stream) {
    const void* x     = d_in[0];
    const void* w_i2h = d_in[1];
    const void* b_i2h = d_in[2];
    // d_in[3]=w_h2h, d_in[4]=b_h2h: dead code (reference overwrites hidden=transformed)
    const void* w_i2c = d_in[5];
    const void* b_i2c = d_in[6];
    const void* w_c2c = d_in[7];
    const void* b_c2c = d_in[8];
    const void* w_c2t = d_in[9];
    const void* b_c2t = d_in[10];
    const int* ns     = (const int*)d_in[11];

    // ws layout: ip bf16 [2048,256] | ctx_hist bf16 | cin f32 | flag | outT f32
    unsigned short* ip  = (unsigned short*)d_ws;
    unsigned short* ch  = (unsigned short*)((char*)d_ws + (size_t)MM*HH*2);
    float* cin          = (float*)((char*)d_ws + (size_t)MM*HH*4);
    int* flag           = (int*)((char*)d_ws + (size_t)MM*HH*8);
    float* outT         = (float*)((char*)d_ws + (size_t)MM*HH*8 + 1024);

    // allow 160 KiB dynamic LDS for k3 (host-side attribute; capture-safe)
    (void)hipFuncSetAttribute((const void*)k3_main,
                              hipFuncAttributeMaxDynamicSharedMemorySize, 163840);

    k0_sniff<<<1, 256, 0, stream>>>((const unsigned short*)x, flag);
    k1_proj<<<64, 256, 0, stream>>>(x, w_i2h, b_i2h, w_i2c, b_i2c, flag, ip, cin);
    k2_ctx<<<BB, 512, 0, stream>>>(w_c2c, b_c2c, cin, ns, flag, ch, d_out);
    k3_main<<<256, 512, 163840, stream>>>(ch, w_c2t, b_c2t, ip, flag, outT);
    k4_tr<<<dim3(32, 4), 256, 0, stream>>>(outT, flag, d_out);
}

// Round 9
// 431.086 us; speedup vs baseline: 1.3842x; 1.0837x over previous
//
#include <hip/hip_runtime.h>

// Problem constants (T=64, B=32, I=128, H=256, alpha=0.2)
#define TT 64
#define BB 32
#define II 128
#define HH 256
#define MM (TT*BB)   // 2048

typedef __bf16  bf16x8  __attribute__((ext_vector_type(8)));
typedef float   f32x16  __attribute__((ext_vector_type(16)));
typedef _Float16 half2v __attribute__((ext_vector_type(2)));

__device__ __forceinline__ float bf2f(unsigned short u) {
    union { unsigned int i; float f; } v; v.i = ((unsigned int)u) << 16; return v.f;
}
__device__ __forceinline__ unsigned short f2bf(float f) {
    union { float f; unsigned int i; } v; v.f = f;
    unsigned int r = v.i + 0x7fffu + ((v.i >> 16) & 1u);
    return (unsigned short)(r >> 16);
}

// Dual-dtype loaders: external tensors may be fp32 or bf16; runtime flag decides.
struct F8 { float v[8]; };
__device__ __forceinline__ F8 load8(const void* base, int idx, int isf32) {
    F8 r;
    if (isf32) {
        const float4* p = (const float4*)((const float*)base + idx);
        float4 a = p[0], b = p[1];
        r.v[0]=a.x; r.v[1]=a.y; r.v[2]=a.z; r.v[3]=a.w;
        r.v[4]=b.x; r.v[5]=b.y; r.v[6]=b.z; r.v[7]=b.w;
    } else {
        uint4 u = *(const uint4*)((const unsigned short*)base + idx);
        const unsigned short* p = (const unsigned short*)&u;
#pragma unroll
        for (int j = 0; j < 8; ++j) r.v[j] = bf2f(p[j]);
    }
    return r;
}
__device__ __forceinline__ float load1(const void* base, int idx, int isf32) {
    return isf32 ? ((const float*)base)[idx]
                 : bf2f(((const unsigned short*)base)[idx]);
}

__device__ __forceinline__ float fdot2f(half2v a, half2v b, float c) {
#if __has_builtin(__builtin_amdgcn_fdot2)
    return __builtin_amdgcn_fdot2(a, b, c, false);
#else
    return c + (float)a.x*(float)b.x + (float)a.y*(float)b.y;
#endif
}

// ---------------------------------------------------------------------------
// K0: dtype sniffer (fp32 read as ushorts -> ~25% have exponent >= 0xC0).
// ---------------------------------------------------------------------------
__global__ __launch_bounds__(256) void k0_sniff(
    const unsigned short* __restrict__ x, int* __restrict__ flag)
{
    __shared__ int cnt;
    if (threadIdx.x == 0) cnt = 0;
    __syncthreads();
    int c = 0;
    for (int i = threadIdx.x; i < 8192; i += 256) {
        unsigned int e = (x[i] >> 7) & 0xFFu;
        if (e >= 0xC0u) ++c;
    }
    atomicAdd(&cnt, c);
    __syncthreads();
    if (threadIdx.x == 0) flag[0] = (cnt > 16) ? 1 : 0;
}

// ---------------------------------------------------------------------------
// K1 v3 (unchanged): weights in VGPRs; two-phase (load blob -> dot) per m-row.
// ---------------------------------------------------------------------------
__global__ __launch_bounds__(256) void k1_proj(
    const void* __restrict__ x,
    const void* __restrict__ w_i2h,
    const void* __restrict__ b_i2h,
    const void* __restrict__ w_i2c,
    const void* __restrict__ b_i2c,
    const int* __restrict__ flagp,
    unsigned short* __restrict__ ip,
    float* __restrict__ cin)
{
    const int isf32 = *flagp;
    const int tid = threadIdx.x;
    const int h = tid;
    const int mbase = blockIdx.x * 32;
    __shared__ __align__(16) _Float16 xs[32][II];   // 8 KB

    half2v w1[II/2], w2[II/2];
#pragma unroll
    for (int c8 = 0; c8 < II/8; ++c8) {
        F8 f1 = load8(w_i2h, h*II + c8*8, isf32);
        F8 f2 = load8(w_i2c, h*II + c8*8, isf32);
#pragma unroll
        for (int j = 0; j < 4; ++j) {
            half2v a; a.x = (_Float16)f1.v[2*j]; a.y = (_Float16)f1.v[2*j+1];
            half2v b; b.x = (_Float16)f2.v[2*j]; b.y = (_Float16)f2.v[2*j+1];
            w1[c8*4 + j] = a;
            w2[c8*4 + j] = b;
        }
    }
    const float bb1 = load1(b_i2h, h, isf32);
    const float bb2 = load1(b_i2c, h, isf32);

    for (int u = tid; u < 32*II; u += 256)
        xs[u >> 7][u & (II-1)] = (_Float16)load1(x, (mbase + (u >> 7))*II + (u & (II-1)), isf32);
    __syncthreads();

    for (int mm = 0; mm < 32; ++mm) {
        const float4* xv4 = (const float4*)xs[mm];   // 16 x float4 = 128 halves
        float4 blob[16];
#pragma unroll
        for (int r = 0; r < 16; ++r) blob[r] = xv4[r];
        float a0=0,a1=0,a2=0,a3=0, c0=0,c1=0,c2=0,c3=0;
#pragma unroll
        for (int r = 0; r < 16; ++r) {
            const half2v* xc = (const half2v*)&blob[r];
            a0 = fdot2f(w1[r*4+0], xc[0], a0);
            a1 = fdot2f(w1[r*4+1], xc[1], a1);
            a2 = fdot2f(w1[r*4+2], xc[2], a2);
            a3 = fdot2f(w1[r*4+3], xc[3], a3);
            c0 = fdot2f(w2[r*4+0], xc[0], c0);
            c1 = fdot2f(w2[r*4+1], xc[1], c1);
            c2 = fdot2f(w2[r*4+2], xc[2], c2);
            c3 = fdot2f(w2[r*4+3], xc[3], c3);
        }
        ip[(mbase+mm)*HH + h]  = f2bf(((a0+a1)+(a2+a3)) + bb1);
        cin[(mbase+mm)*HH + h] = ((c0+c1)+(c2+c3)) + bb2;
    }
}

// ---------------------------------------------------------------------------
// K2 v3 (unchanged): 512 threads, k split in half, two-phase load->dot.
// ---------------------------------------------------------------------------
__global__ __launch_bounds__(512) void k2_ctx(
    const void* __restrict__ w_c2c,
    const void* __restrict__ b_c2c,
    const float* __restrict__ cin,
    const int* __restrict__ ns_ptr,
    const int* __restrict__ flagp,
    unsigned short* __restrict__ ctx_hist,
    void* __restrict__ out_base)
{
    const int isf32 = *flagp;
    const int b = blockIdx.x;
    const int tid = threadIdx.x;
    const int h  = tid & 255;
    const int kh = tid >> 8;
    const int ns = max(1, *ns_ptr);

    __shared__ __align__(16) _Float16 cs[2][HH];
    __shared__ __align__(16) float part[2][HH];

    half2v w[64];
#pragma unroll
    for (int c8 = 0; c8 < 16; ++c8) {
        F8 f = load8(w_c2c, h*HH + kh*128 + c8*8, isf32);
#pragma unroll
        for (int j = 0; j < 4; ++j) {
            half2v hv;
            hv.x = (_Float16)f.v[2*j];
            hv.y = (_Float16)f.v[2*j+1];
            w[c8*4 + j] = hv;
        }
    }
    const float bcc = (kh == 0) ? load1(b_c2c, h, isf32) : 0.0f;
    float ctxv = 0.0f;
    if (kh == 0) cs[0][h] = (_Float16)0.0f;
    __syncthreads();
    int cur = 0;

    for (int t = 0; t < TT; ++t) {
        const float cinv = (kh == 0) ? cin[(t*BB + b)*HH + h] : 0.0f;
        for (int s = 0; s < ns; ++s) {
            if (kh == 0 && s == ns-1) ctx_hist[(t*BB + b)*HH + h] = f2bf(ctxv);
            float4 blob[16];
            const float4* cp4 = (const float4*)cs[cur] + kh*16;
#pragma unroll
            for (int r = 0; r < 16; ++r) blob[r] = cp4[r];
            float p0=0,p1=0,p2=0,p3=0;
#pragma unroll
            for (int r = 0; r < 16; ++r) {
                const half2v* c2 = (const half2v*)&blob[r];
                p0 = fdot2f(w[r*4+0], c2[0], p0);
                p1 = fdot2f(w[r*4+1], c2[1], p1);
                p2 = fdot2f(w[r*4+2], c2[2], p2);
                p3 = fdot2f(w[r*4+3], c2[3], p3);
            }
            part[kh][h] = ((p0+p1)+(p2+p3));
            __syncthreads();
            if (kh == 0) {
                float cnew = fmaxf(part[0][h] + part[1][h] + bcc + cinv, 0.0f);
                ctxv = 0.8f*ctxv + 0.2f*cnew;
                cs[cur^1][h] = (_Float16)ctxv;
            }
            cur ^= 1;
            __syncthreads();
        }
    }
    if (kh == 0) {
        const int cofs = MM*HH + BB*HH + b*HH + h;
        if (isf32) ((float*)out_base)[cofs] = ctxv;
        else       ((unsigned short*)out_base)[cofs] = f2bf(ctxv);
    }
}

// ---------------------------------------------------------------------------
// K3 v8: barrier-free K-loop. R8 was barrier-convoy bound (144 barriers, 1
// block/CU, all pipes <15%). Fix: A is loaded DIRECTLY from global as MFMA
// fragments (lane l: row mh*32+(l&31), 8 contiguous k at (l>>5)*8 — one 16B
// load). ctx is 1 MB -> L2-resident; no As region, no staging barriers. The
// entire mc's 16-step K loop runs with zero barriers; waves free-run and the
// compiler pipelines vmcnt/lgkmcnt. LDS: Bs 128 KB + dedicated TM 32 KB.
// Barriers: 4/mc (epilogue only). Wave tile 32m x 128j, acc = 64 VGPRs.
// ---------------------------------------------------------------------------
__global__ __launch_bounds__(512, 1) void k3_main(
    const unsigned short* __restrict__ ctx_hist,  // [2048,256] bf16 (internal)
    const void* __restrict__ wc,                  // [65536,256] external
    const void* __restrict__ bc,                  // [65536]     external
    const unsigned short* __restrict__ ip,        // [2048,256] bf16 (internal)
    const int* __restrict__ flagp,
    float* __restrict__ outT)                     // [256 i][2048 m] f32 (ws)
{
    extern __shared__ __align__(16) unsigned char lds[];
    unsigned short* Bs  = (unsigned short*)lds;             // 131072 B
    unsigned short* TMh = (unsigned short*)(lds + 131072);  // 32768 B [64][256]

    const int isf32 = *flagp;
    const int tid  = threadIdx.x;
    const int lane = tid & 63;
    const int wave = tid >> 6;        // 0..7
    const int i    = blockIdx.x;      // 0..255
    const int mh   = wave & 3;        // m-subblock (32 rows)
    const int jh   = wave >> 2;       // j-half (128 cols)
    const int l31  = lane & 31;
    const int lhi  = lane >> 5;

    // epilogue per-lane bc for cols 4*lane..4*lane+3
    float bcl[4];
#pragma unroll
    for (int q = 0; q < 4; ++q)
        bcl[q] = load1(bc, i*HH + 4*lane + q, isf32);

    // ---- stage B once: fragment-major, conflict-free (verified R6-R8) ----
#pragma unroll
    for (int p = 0; p < 16; ++p) {
        int u = tid + p*512;
        int row = u >> 5, cu = u & 31;
        F8 f = load8(wc, (i*HH + row)*HH + cu*8, isf32);
        unsigned short tmp[8];
#pragma unroll
        for (int j = 0; j < 8; ++j) tmp[j] = f2bf(f.v[j]);
        int unit = cu*256 + (row & ~7) + ((row & 7) ^ (cu & 7));
        *(uint4*)(Bs + unit*8) = *(const uint4*)tmp;
    }
    __syncthreads();   // B visible to all waves; last block-wide staging sync

    // B row indices for this wave's 4 j-columns (fixed all kernel)
    int rbh[4], rbl[4];
#pragma unroll
    for (int n = 0; n < 4; ++n) {
        int rb = jh*128 + n*32 + l31;
        rbh[n] = rb & ~7;
        rbl[n] = rb & 7;
    }

    for (int mc = 0; mc < 16; ++mc) {
        const int m0 = mc * 128;
        // this lane's A row pointer (fragment-direct from global, L2-hot)
        const unsigned short* aptr = ctx_hist + (m0 + mh*32 + l31)*HH + lhi*8;

        f32x16 acc[4];
#pragma unroll
        for (int n = 0; n < 4; ++n)
#pragma unroll
            for (int r = 0; r < 16; ++r) acc[n][r] = 0.0f;

#pragma unroll 4
        for (int ks = 0; ks < 16; ++ks) {
            bf16x8 a0 = *(const bf16x8*)(aptr + ks*16);
            const int cB = ks*2 + lhi;          // 0..31
            const int cx = cB & 7;
            bf16x8 b0 = *(const bf16x8*)(Bs + (cB*256 + rbh[0] + (rbl[0] ^ cx))*8);
            bf16x8 b1 = *(const bf16x8*)(Bs + (cB*256 + rbh[1] + (rbl[1] ^ cx))*8);
            bf16x8 b2 = *(const bf16x8*)(Bs + (cB*256 + rbh[2] + (rbl[2] ^ cx))*8);
            bf16x8 b3 = *(const bf16x8*)(Bs + (cB*256 + rbh[3] + (rbl[3] ^ cx))*8);
            acc[0] = __builtin_amdgcn_mfma_f32_32x32x16_bf16(a0, b0, acc[0], 0, 0, 0);
            acc[1] = __builtin_amdgcn_mfma_f32_32x32x16_bf16(a0, b1, acc[1], 0, 0, 0);
            acc[2] = __builtin_amdgcn_mfma_f32_32x32x16_bf16(a0, b2, acc[2], 0, 0, 0);
            acc[3] = __builtin_amdgcn_mfma_f32_32x32x16_bf16(a0, b3, acc[3], 0, 0, 0);
        }

        // ---- epilogue: 2 phases of 64 m-rows; TM bf16 [64][256] dedicated --
#pragma unroll
        for (int ph = 0; ph < 2; ++ph) {
            if ((mh >> 1) == ph) {
#pragma unroll
                for (int n = 0; n < 4; ++n) {
                    const int col = jh*128 + n*32 + l31;
#pragma unroll
                    for (int r = 0; r < 16; ++r) {
                        const int rowl = (mh & 1)*32 + (r & 3) + 8*(r >> 2) + 4*lhi;
                        TMh[rowl*256 + col] = f2bf(acc[n][r]);
                    }
                }
            }
            __syncthreads();
#pragma unroll 2
            for (int rep = 0; rep < 8; ++rep) {
                const int rowg = wave*8 + rep;                 // 0..63
                const int g = m0 + ph*64 + rowg;               // global m
                uint2 tm2 = *(const uint2*)(TMh + rowg*256 + 4*lane);
                uint2 ip2 = *(const uint2*)(ip + g*HH + 4*lane);
                const unsigned short* tp = (const unsigned short*)&tm2;
                const unsigned short* pp = (const unsigned short*)&ip2;
                float s = 0.0f;
#pragma unroll
                for (int q = 0; q < 4; ++q)
                    s = fmaf(bf2f(tp[q]) + bcl[q], bf2f(pp[q]), s);
                s += __shfl_xor(s, 1);
                s += __shfl_xor(s, 2);
                s += __shfl_xor(s, 4);
                s += __shfl_xor(s, 8);
                s += __shfl_xor(s, 16);
                s += __shfl_xor(s, 32);
                if (lane == rep) outT[(size_t)i*MM + g] = s;
            }
            __syncthreads();
        }
    }
}

// ---------------------------------------------------------------------------
// K4: transpose outT[256 i][2048 m] f32 -> out[m][i] (+ final-hidden chunk).
// ---------------------------------------------------------------------------
__global__ __launch_bounds__(256) void k4_tr(
    const float* __restrict__ outT,
    const int* __restrict__ flagp,
    void* __restrict__ out)
{
    const int isf32 = *flagp;
    __shared__ float tile[64][65];
    const int m0 = blockIdx.x * 64, i0 = blockIdx.y * 64;
    const int tm = threadIdx.x & 63, tq = threadIdx.x >> 6;   // tq 0..3
#pragma unroll
    for (int rep = 0; rep < 16; ++rep) {
        int il = tq + rep*4;
        tile[il][tm] = outT[(size_t)(i0 + il)*MM + m0 + tm];
    }
    __syncthreads();
#pragma unroll
    for (int rep = 0; rep < 16; ++rep) {
        int ml = tq + rep*4;
        int ii = tm;
        float v = tile[ii][ml];
        int mg = m0 + ml, ig = i0 + ii;
        if (isf32) {
            float* o = (float*)out;
            o[(size_t)mg*HH + ig] = v;
            if (mg >= MM - BB) o[(size_t)MM*HH + (mg - (MM-BB))*HH + ig] = v;
        } else {
            unsigned short* o = (unsigned short*)out;
            unsigned short b = f2bf(v);
            o[(size_t)mg*HH + ig] = b;
            if (mg >= MM - BB) o[(size_t)MM*HH + (mg - (MM-BB))*HH + ig] = b;
        }
    }
}

// ---------------------------------------------------------------------------
extern "C" void kernel_launch(void* const* d_in, const int* in_sizes, int n_in,
                              void* d_out, int out_size, void* d_ws, size_t ws_size,
                              hipStream_t stream) {
    const void* x     = d_in[0];
    const void* w_i2h = d_in[1];
    const void* b_i2h = d_in[2];
    // d_in[3]=w_h2h, d_in[4]=b_h2h: dead code (reference overwrites hidden=transformed)
    const void* w_i2c = d_in[5];
    const void* b_i2c = d_in[6];
    const void* w_c2c = d_in[7];
    const void* b_c2c = d_in[8];
    const void* w_c2t = d_in[9];
    const void* b_c2t = d_in[10];
    const int* ns     = (const int*)d_in[11];

    // ws layout: ip bf16 [2048,256] | ctx_hist bf16 | cin f32 | flag | outT f32
    unsigned short* ip  = (unsigned short*)d_ws;
    unsigned short* ch  = (unsigned short*)((char*)d_ws + (size_t)MM*HH*2);
    float* cin          = (float*)((char*)d_ws + (size_t)MM*HH*4);
    int* flag           = (int*)((char*)d_ws + (size_t)MM*HH*8);
    float* outT         = (float*)((char*)d_ws + (size_t)MM*HH*8 + 1024);

    // allow 160 KiB dynamic LDS for k3 (host-side attribute; capture-safe)
    (void)hipFuncSetAttribute((const void*)k3_main,
                              hipFuncAttributeMaxDynamicSharedMemorySize, 163840);

    k0_sniff<<<1, 256, 0, stream>>>((const unsigned short*)x, flag);
    k1_proj<<<64, 256, 0, stream>>>(x, w_i2h, b_i2h, w_i2c, b_i2c, flag, ip, cin);
    k2_ctx<<<BB, 512, 0, stream>>>(w_c2c, b_c2c, cin, ns, flag, ch, d_out);
    k3_main<<<256, 512, 163840, stream>>>(ch, w_c2t, b_c2t, ip, flag, outT);
    k4_tr<<<dim3(32, 4), 256, 0, stream>>>(outT, flag, d_out);
}